// Round 2
// baseline (219.709 us; speedup 1.0000x reference)
//
#include <hip/hip_runtime.h>
#include <hip/hip_bf16.h>

// TurboQuantMSE: x_hat = Q(x @ R^T) @ R, Q = 16-level Lloyd-Max quantizer.
// fp16 MFMA for both GEMMs (m97 128x128 NT structure), quantize fused into
// GEMM1 epilogue. fp16 (2^-11) instead of bf16 (2^-9) input rounding: GEMM1
// error drives quantizer boundary flips (all 15 boundaries in |y|<0.038,
// spacing ~0.004; bf16 GEMM error sigma ~1.6e-3 caused absmax 4.4e-3 > 4.28e-3
// threshold). fp16 cuts flip-induced error ~2x -> ~2.2e-3.

typedef __attribute__((ext_vector_type(8))) _Float16 f16x8;
typedef __attribute__((ext_vector_type(4))) float f32x4;

__device__ __forceinline__ unsigned short f2h(float f) {
    _Float16 h = (_Float16)f;
    return *reinterpret_cast<unsigned short*>(&h);
}

// ---------------- elementwise f32 -> fp16 (x) ----------------
__global__ __launch_bounds__(256) void convert_x_kernel(
    const float* __restrict__ x, unsigned short* __restrict__ xb) {
    const int i = (blockIdx.x * 256 + threadIdx.x) * 4;
    float4 v = *reinterpret_cast<const float4*>(x + i);
    ushort4 b;
    b.x = f2h(v.x); b.y = f2h(v.y); b.z = f2h(v.z); b.w = f2h(v.w);
    *reinterpret_cast<ushort4*>(xb + i) = b;
}

// ---------------- rotation f32 -> fp16 (row-major) + fp16 transposed --------
// 64x64 tile per block through padded LDS for the transposed write.
__global__ __launch_bounds__(256) void conv_rot_kernel(
    const float* __restrict__ R, unsigned short* __restrict__ Rb,
    unsigned short* __restrict__ Rt) {
    __shared__ float t[64][65];
    const int tid = threadIdx.x;
    const int tr = blockIdx.y * 64, tc = blockIdx.x * 64;
    const int r0 = tid >> 4;            // 0..15
    const int c4 = (tid & 15) << 2;     // 0..60 step 4
#pragma unroll
    for (int i = 0; i < 4; i++) {
        const int r = r0 + i * 16;
        float4 v = *reinterpret_cast<const float4*>(
            &R[(size_t)(tr + r) * 4096 + tc + c4]);
        ushort4 b;
        b.x = f2h(v.x); b.y = f2h(v.y); b.z = f2h(v.z); b.w = f2h(v.w);
        *reinterpret_cast<ushort4*>(&Rb[(size_t)(tr + r) * 4096 + tc + c4]) = b;
        t[r][c4 + 0] = v.x; t[r][c4 + 1] = v.y;
        t[r][c4 + 2] = v.z; t[r][c4 + 3] = v.w;
    }
    __syncthreads();
#pragma unroll
    for (int i = 0; i < 16; i++) {
        const int idx = tid + 256 * i;
        const int rr = idx >> 6;        // out row within tile (= original col)
        const int cc = idx & 63;        // out col within tile (= original row)
        Rt[(size_t)(tc + rr) * 4096 + tr + cc] = f2h(t[cc][rr]);
    }
}

// ---------------- NT GEMM, 128x128x32 tile, 4 waves, m97 structure ----------
// C[M,N] = A[M,K] * Bt[N,K]^T ; A,Bt fp16 row-major; f32 accum.
// QUANT: epilogue quantizes y*64 to nearest Lloyd-Max centroid, writes fp16
//        centroid/64. Else writes f32.
template <bool QUANT>
__global__ __launch_bounds__(256, 2) void gemm_nt_kernel(
    const unsigned short* __restrict__ A, const unsigned short* __restrict__ Bt,
    void* __restrict__ Cout, const float* __restrict__ cb) {
    constexpr int N = 4096, K = 4096;
    constexpr int BM = 128, BN = 128, BK = 32;
    __shared__ __align__(16) unsigned short Atile[BM * BK];
    __shared__ __align__(16) unsigned short Btile[BN * BK];

    const int tid = threadIdx.x;
    const int lane = tid & 63;
    const int w = tid >> 6;       // wave 0..3
    const int wm = w >> 1, wn = w & 1;

    // XCD-aware swizzle (nwg=512, divisible by 8 -> bijective)
    const int bid = blockIdx.x;
    const int nwg = gridDim.x;
    const int wgid = (bid & 7) * (nwg >> 3) + (bid >> 3);
    const int tn = wgid & 31;     // N/BN = 32
    const int tm = wgid >> 5;

    f32x4 acc[4][4];
#pragma unroll
    for (int m = 0; m < 4; m++)
#pragma unroll
        for (int n = 0; n < 4; n++) acc[m][n] = (f32x4){0.f, 0.f, 0.f, 0.f};

    // staging: each thread issues 4x global_load_lds width-16 per K-step.
    const int srow = (w << 4) + (lane >> 2);   // row within 64-row group
    const int scol = (lane & 3) << 3;          // 0,8,16,24
    const unsigned short* Ap0 = A + (size_t)(tm * BM + srow) * K + scol;
    const unsigned short* Ap1 = Ap0 + (size_t)64 * K;
    const unsigned short* Bp0 = Bt + (size_t)(tn * BN + srow) * K + scol;
    const unsigned short* Bp1 = Bp0 + (size_t)64 * K;
    unsigned short* Al0 = &Atile[(w << 4) * BK];
    unsigned short* Al1 = &Atile[((w << 4) + 64) * BK];
    unsigned short* Bl0 = &Btile[(w << 4) * BK];
    unsigned short* Bl1 = &Btile[((w << 4) + 64) * BK];

    // fragment read offsets (A: row=wm*64+m*16+(lane&15), kchunk=(lane>>4)*8)
    const int aoff = (wm * 64 + (lane & 15)) * BK + ((lane >> 4) << 3);
    const int boff = (wn * 64 + (lane & 15)) * BK + ((lane >> 4) << 3);

    for (int k0 = 0; k0 < K; k0 += BK) {
        __builtin_amdgcn_global_load_lds(
            (const __attribute__((address_space(1))) void*)Ap0,
            (__attribute__((address_space(3))) void*)Al0, 16, 0, 0);
        __builtin_amdgcn_global_load_lds(
            (const __attribute__((address_space(1))) void*)Ap1,
            (__attribute__((address_space(3))) void*)Al1, 16, 0, 0);
        __builtin_amdgcn_global_load_lds(
            (const __attribute__((address_space(1))) void*)Bp0,
            (__attribute__((address_space(3))) void*)Bl0, 16, 0, 0);
        __builtin_amdgcn_global_load_lds(
            (const __attribute__((address_space(1))) void*)Bp1,
            (__attribute__((address_space(3))) void*)Bl1, 16, 0, 0);
        Ap0 += BK; Ap1 += BK; Bp0 += BK; Bp1 += BK;
        __syncthreads();

        f16x8 af[4], bfr[4];
#pragma unroll
        for (int m = 0; m < 4; m++)
            af[m] = *reinterpret_cast<const f16x8*>(&Atile[aoff + m * 16 * BK]);
#pragma unroll
        for (int n = 0; n < 4; n++)
            bfr[n] = *reinterpret_cast<const f16x8*>(&Btile[boff + n * 16 * BK]);
#pragma unroll
        for (int m = 0; m < 4; m++)
#pragma unroll
            for (int n = 0; n < 4; n++)
                acc[m][n] = __builtin_amdgcn_mfma_f32_16x16x32_f16(
                    af[m], bfr[n], acc[m][n], 0, 0, 0);
        __syncthreads();
    }

    // epilogue: C/D layout col=lane&15, row=(lane>>4)*4+j  [m89-verified]
    const int crow0 = tm * BM + wm * 64 + ((lane >> 4) << 2);
    const int ccol0 = tn * BN + wn * 64 + (lane & 15);
    if constexpr (QUANT) {
        float c[16];
#pragma unroll
        for (int i = 0; i < 16; i++) c[i] = cb[i];
        unsigned short* O = (unsigned short*)Cout;
#pragma unroll
        for (int m = 0; m < 4; m++)
#pragma unroll
            for (int n = 0; n < 4; n++)
#pragma unroll
                for (int j = 0; j < 4; j++) {
                    const float yn = acc[m][n][j] * 64.0f;
                    float v = c[0];
#pragma unroll
                    for (int i = 0; i < 15; i++) {
                        const float bnd = 0.5f * (c[i] + c[i + 1]);
                        v = (yn > bnd) ? c[i + 1] : v;
                    }
                    const int row = crow0 + m * 16 + j;
                    const int col = ccol0 + n * 16;
                    O[(size_t)row * N + col] = f2h(v * 0.015625f);
                }
    } else {
        float* O = (float*)Cout;
#pragma unroll
        for (int m = 0; m < 4; m++)
#pragma unroll
            for (int n = 0; n < 4; n++)
#pragma unroll
                for (int j = 0; j < 4; j++) {
                    const int row = crow0 + m * 16 + j;
                    const int col = ccol0 + n * 16;
                    O[(size_t)row * N + col] = acc[m][n][j];
                }
    }
}

extern "C" void kernel_launch(void* const* d_in, const int* in_sizes, int n_in,
                              void* d_out, int out_size, void* d_ws,
                              size_t ws_size, hipStream_t stream) {
    const float* x = (const float*)d_in[0];
    const float* rot = (const float*)d_in[1];
    const float* cb = (const float*)d_in[2];
    float* out = (float*)d_out;

    // workspace layout (fp16 elements): Xh 8M | Rh 16M | Rt 16M | Yh 8M = 96MB
    unsigned short* Xh = (unsigned short*)d_ws;
    unsigned short* Rh = Xh + (size_t)2048 * 4096;
    unsigned short* Rt = Rh + (size_t)4096 * 4096;
    unsigned short* Yh = Rt + (size_t)4096 * 4096;

    convert_x_kernel<<<8192, 256, 0, stream>>>(x, Xh);
    conv_rot_kernel<<<dim3(64, 64), 256, 0, stream>>>(rot, Rh, Rt);
    // y = x @ R^T : NT GEMM with Bt = Rh (row-major R is already N x K here)
    gemm_nt_kernel<true><<<512, 256, 0, stream>>>(Xh, Rh, (void*)Yh, cb);
    // x_hat = y_hat @ R = y_hat @ (R^T)^T : NT GEMM with Bt = Rt
    gemm_nt_kernel<false><<<512, 256, 0, stream>>>(Yh, Rt, (void*)out, nullptr);
}

// Round 3
// 172.605 us; speedup vs baseline: 1.2729x; 1.2729x over previous
//
#include <hip/hip_runtime.h>
#include <hip/hip_bf16.h>

// TurboQuantMSE: x_hat = Q(x @ R^T) @ R, Q = 16-level Lloyd-Max quantizer.
// fp16 MFMA GEMMs in the 8-phase counted-vmcnt structure (T2+T3+T4+T5):
// 128x256 tile, BK=64, 8 waves, TRIPLE-buffered LDS (144KB dynamic) so the
// tile-boundary wait is a counted vmcnt(2), never a drain. LDS XOR-swizzle
// (slot ^= row&7) kills the 16-way ds_read_b128 bank conflict; applied as
// pre-swizzled global source (linear global_load_lds dest) + swizzled read.

typedef __attribute__((ext_vector_type(8))) _Float16 f16x8;
typedef __attribute__((ext_vector_type(4))) float f32x4;

__device__ __forceinline__ unsigned short f2h(float f) {
    _Float16 h = (_Float16)f;
    return *reinterpret_cast<unsigned short*>(&h);
}

// ---------------- elementwise f32 -> fp16 (x) ----------------
__global__ __launch_bounds__(256) void convert_x_kernel(
    const float* __restrict__ x, unsigned short* __restrict__ xb) {
    const int i = (blockIdx.x * 256 + threadIdx.x) * 4;
    float4 v = *reinterpret_cast<const float4*>(x + i);
    ushort4 b;
    b.x = f2h(v.x); b.y = f2h(v.y); b.z = f2h(v.z); b.w = f2h(v.w);
    *reinterpret_cast<ushort4*>(xb + i) = b;
}

// ---------------- rotation f32 -> fp16 (row-major) + fp16 transposed --------
__global__ __launch_bounds__(256) void conv_rot_kernel(
    const float* __restrict__ R, unsigned short* __restrict__ Rb,
    unsigned short* __restrict__ Rt) {
    __shared__ float t[64][65];
    const int tid = threadIdx.x;
    const int tr = blockIdx.y * 64, tc = blockIdx.x * 64;
    const int r0 = tid >> 4;
    const int c4 = (tid & 15) << 2;
#pragma unroll
    for (int i = 0; i < 4; i++) {
        const int r = r0 + i * 16;
        float4 v = *reinterpret_cast<const float4*>(
            &R[(size_t)(tr + r) * 4096 + tc + c4]);
        ushort4 b;
        b.x = f2h(v.x); b.y = f2h(v.y); b.z = f2h(v.z); b.w = f2h(v.w);
        *reinterpret_cast<ushort4*>(&Rb[(size_t)(tr + r) * 4096 + tc + c4]) = b;
        t[r][c4 + 0] = v.x; t[r][c4 + 1] = v.y;
        t[r][c4 + 2] = v.z; t[r][c4 + 3] = v.w;
    }
    __syncthreads();
#pragma unroll
    for (int i = 0; i < 16; i++) {
        const int idx = tid + 256 * i;
        const int rr = idx >> 6;
        const int cc = idx & 63;
        Rt[(size_t)(tc + rr) * 4096 + tr + cc] = f2h(t[cc][rr]);
    }
}

// ---------------- phased NT GEMM --------------------------------------------
// C[2048,4096] = A[2048,K] * Bt[4096,K]^T, fp16 in, f32 accum.
// BM=128 BN=256 BK=64, 8 waves (2M x 4N), per-wave 64x64 (4x4 frags).
// 3 LDS buffers of (128+256)*64*2B = 48KB. 6 staging chunks/K-tile
// (A:2, B:4), each chunk = 1 global_load_lds(16B)/thread.
// Steady state per K-tile t: ph0 stages B0,B1 of t+1; ph1 stages B2,B3 of
// t+1; ph2 stages A0,A1 of t+2; boundary wait = vmcnt(2) (own 6 loads of
// t+1 retired, t+2's 2 still in flight) + barrier.
constexpr int GK = 4096;
constexpr int BM = 128, BN = 256, BK = 64;
constexpr int NT = GK / BK;                 // 64
constexpr int A_BYTES = BM * BK * 2;        // 16384
constexpr int BUF_BYTES = (BM + BN) * BK * 2;  // 49152
constexpr int LDS_DYN = 3 * BUF_BYTES;      // 147456

template <bool QUANT>
__global__ __launch_bounds__(512, 2) void gemm_nt_kernel(
    const unsigned short* __restrict__ A, const unsigned short* __restrict__ Bt,
    void* __restrict__ Cout, const float* __restrict__ cb16) {
    extern __shared__ char smem[];
    const int tid = threadIdx.x;
    const int lane = tid & 63;
    const int w = tid >> 6;        // 0..7
    const int wm = w >> 2;         // 0..1
    const int wn = w & 3;          // 0..3

    // XCD-aware bijective swizzle (256 blocks, 256%8==0)
    const int bid = blockIdx.x;
    const int wgid = (bid & 7) * 32 + (bid >> 3);
    const int tn = wgid & 15;      // N/BN = 16
    const int tm = wgid >> 4;      // M/BM = 16

    f32x4 acc[4][4];
#pragma unroll
    for (int m = 0; m < 4; m++)
#pragma unroll
        for (int n = 0; n < 4; n++) acc[m][n] = (f32x4){0.f, 0.f, 0.f, 0.f};

    // ---- staging (pre-swizzled global source, linear LDS dest) ----
    const int srow = tid >> 3;                              // 0..63
    const int scol = (((tid & 7) ^ (srow & 7)) << 3);       // elements
    const size_t arow0 = (size_t)(tm * BM) * GK;
    const size_t brow0 = (size_t)(tn * BN) * GK;
    const int wbase = (w << 10);                            // w*1024 B

    auto stage = [&](int tile, int chunk) {
        const int b = tile % 3;
        const int k0 = tile * BK;
        const unsigned short* src;
        int ldsoff;
        if (chunk < 2) {
            src = A + arow0 + (size_t)(chunk * 64 + srow) * GK + k0 + scol;
            ldsoff = b * BUF_BYTES + chunk * 8192 + wbase;
        } else {
            src = Bt + brow0 + (size_t)((chunk - 2) * 64 + srow) * GK + k0 + scol;
            ldsoff = b * BUF_BYTES + A_BYTES + (chunk - 2) * 8192 + wbase;
        }
        __builtin_amdgcn_global_load_lds(
            (const __attribute__((address_space(1))) void*)src,
            (__attribute__((address_space(3))) void*)(smem + ldsoff), 16, 0, 0);
    };

    // ---- fragment read addressing (swizzled) ----
    const int arow = (wm * 64 + (lane & 15)) * 128;           // A row byte
    const int brow = A_BYTES + (wn * 64 + (lane & 15)) * 128; // B row byte
    const int slotx = lane >> 4;                              // 0..3
    const int sw0 = ((slotx ^ (lane & 7)) << 4);              // kk=0
    const int sw1 = (((4 + slotx) ^ (lane & 7)) << 4);        // kk=1

#define LDA(m, sw) (*reinterpret_cast<const f16x8*>(smem + cb + arow + (m) * 2048 + (sw)))
#define LDB(n, sw) (*reinterpret_cast<const f16x8*>(smem + cb + brow + (n) * 2048 + (sw)))
#define MFMA_ROW(aR, r)                                                          \
    acc[r][0] = __builtin_amdgcn_mfma_f32_16x16x32_f16(aR, b0, acc[r][0], 0, 0, 0); \
    acc[r][1] = __builtin_amdgcn_mfma_f32_16x16x32_f16(aR, b1, acc[r][1], 0, 0, 0); \
    acc[r][2] = __builtin_amdgcn_mfma_f32_16x16x32_f16(aR, b2, acc[r][2], 0, 0, 0); \
    acc[r][3] = __builtin_amdgcn_mfma_f32_16x16x32_f16(aR, b3, acc[r][3], 0, 0, 0);
#define PH_SYNC                                        \
    __builtin_amdgcn_s_barrier();                      \
    asm volatile("s_waitcnt lgkmcnt(0)" ::: "memory"); \
    __builtin_amdgcn_sched_barrier(0);

    // ---- prologue: tile0 fully + tile1's A chunks; wait own 6 oldest ----
    stage(0, 0); stage(0, 1); stage(0, 2); stage(0, 3); stage(0, 4); stage(0, 5);
    stage(1, 0); stage(1, 1);
    asm volatile("s_waitcnt vmcnt(2)" ::: "memory");
    __builtin_amdgcn_s_barrier();
    __builtin_amdgcn_sched_barrier(0);

    int cb = 0;
    for (int t = 0; t < NT; ++t) {
        f16x8 a0, a1, a2, a3, b0, b1, b2, b3;
        // ---- phase 0: mh=0, kk=0 ----
        a0 = LDA(0, sw0); a1 = LDA(1, sw0);
        b0 = LDB(0, sw0); b1 = LDB(1, sw0); b2 = LDB(2, sw0); b3 = LDB(3, sw0);
        if (t + 1 < NT) { stage(t + 1, 2); stage(t + 1, 3); }
        PH_SYNC
        __builtin_amdgcn_s_setprio(1);
        MFMA_ROW(a0, 0) MFMA_ROW(a1, 1)
        __builtin_amdgcn_s_setprio(0);
        __builtin_amdgcn_s_barrier();
        // ---- phase 1: mh=1, kk=0 (B regs reused) ----
        a2 = LDA(2, sw0); a3 = LDA(3, sw0);
        if (t + 1 < NT) { stage(t + 1, 4); stage(t + 1, 5); }
        PH_SYNC
        __builtin_amdgcn_s_setprio(1);
        MFMA_ROW(a2, 2) MFMA_ROW(a3, 3)
        __builtin_amdgcn_s_setprio(0);
        __builtin_amdgcn_s_barrier();
        // ---- phase 2: mh=0, kk=1 ----
        a0 = LDA(0, sw1); a1 = LDA(1, sw1);
        b0 = LDB(0, sw1); b1 = LDB(1, sw1); b2 = LDB(2, sw1); b3 = LDB(3, sw1);
        if (t + 2 < NT) { stage(t + 2, 0); stage(t + 2, 1); }
        PH_SYNC
        __builtin_amdgcn_s_setprio(1);
        MFMA_ROW(a0, 0) MFMA_ROW(a1, 1)
        __builtin_amdgcn_s_setprio(0);
        __builtin_amdgcn_s_barrier();
        // ---- phase 3: mh=1, kk=1 ----
        a2 = LDA(2, sw1); a3 = LDA(3, sw1);
        PH_SYNC
        __builtin_amdgcn_s_setprio(1);
        MFMA_ROW(a2, 2) MFMA_ROW(a3, 3)
        __builtin_amdgcn_s_setprio(0);
        // ---- tile boundary: counted wait for next buffer's 6 chunks ----
        if (t + 1 < NT) {
            if (t + 2 < NT) {
                asm volatile("s_waitcnt vmcnt(2)" ::: "memory");
            } else {
                asm volatile("s_waitcnt vmcnt(0)" ::: "memory");
            }
            __builtin_amdgcn_s_barrier();
            __builtin_amdgcn_sched_barrier(0);
        }
        cb = (cb == 2 * BUF_BYTES) ? 0 : cb + BUF_BYTES;
    }
#undef LDA
#undef LDB
#undef MFMA_ROW
#undef PH_SYNC

    // ---- epilogue: C/D layout col=lane&15, row=(lane>>4)*4+j ----
    const int crow0 = tm * BM + wm * 64 + ((lane >> 4) << 2);
    const int ccol0 = tn * BN + wn * 64 + (lane & 15);
    if constexpr (QUANT) {
        float c[16];
#pragma unroll
        for (int i = 0; i < 16; i++) c[i] = cb16[i];
        unsigned short* O = (unsigned short*)Cout;
#pragma unroll
        for (int m = 0; m < 4; m++)
#pragma unroll
            for (int n = 0; n < 4; n++)
#pragma unroll
                for (int j = 0; j < 4; j++) {
                    const float yn = acc[m][n][j] * 64.0f;
                    float v = c[0];
#pragma unroll
                    for (int i = 0; i < 15; i++) {
                        const float bnd = 0.5f * (c[i] + c[i + 1]);
                        v = (yn > bnd) ? c[i + 1] : v;
                    }
                    O[(size_t)(crow0 + m * 16 + j) * 4096 + ccol0 + n * 16] =
                        f2h(v * 0.015625f);
                }
    } else {
        float* O = (float*)Cout;
#pragma unroll
        for (int m = 0; m < 4; m++)
#pragma unroll
            for (int n = 0; n < 4; n++)
#pragma unroll
                for (int j = 0; j < 4; j++)
                    O[(size_t)(crow0 + m * 16 + j) * 4096 + ccol0 + n * 16] =
                        acc[m][n][j];
    }
}

extern "C" void kernel_launch(void* const* d_in, const int* in_sizes, int n_in,
                              void* d_out, int out_size, void* d_ws,
                              size_t ws_size, hipStream_t stream) {
    const float* x = (const float*)d_in[0];
    const float* rot = (const float*)d_in[1];
    const float* cb = (const float*)d_in[2];
    float* out = (float*)d_out;

    unsigned short* Xh = (unsigned short*)d_ws;
    unsigned short* Rh = Xh + (size_t)2048 * 4096;
    unsigned short* Rt = Rh + (size_t)4096 * 4096;
    unsigned short* Yh = Rt + (size_t)4096 * 4096;

    (void)hipFuncSetAttribute(
        reinterpret_cast<const void*>(&gemm_nt_kernel<true>),
        hipFuncAttributeMaxDynamicSharedMemorySize, LDS_DYN);
    (void)hipFuncSetAttribute(
        reinterpret_cast<const void*>(&gemm_nt_kernel<false>),
        hipFuncAttributeMaxDynamicSharedMemorySize, LDS_DYN);

    convert_x_kernel<<<8192, 256, 0, stream>>>(x, Xh);
    conv_rot_kernel<<<dim3(64, 64), 256, 0, stream>>>(rot, Rh, Rt);
    // y = x @ R^T : NT GEMM, Bt = Rh
    gemm_nt_kernel<true><<<256, 512, LDS_DYN, stream>>>(Xh, Rh, (void*)Yh, cb);
    // x_hat = y_hat @ R = y_hat @ (R^T)^T : NT GEMM, Bt = Rt
    gemm_nt_kernel<false><<<256, 512, LDS_DYN, stream>>>(Yh, Rt, (void*)out, nullptr);
}

// Round 4
// 172.392 us; speedup vs baseline: 1.2745x; 1.0012x over previous
//
#include <hip/hip_runtime.h>
#include <hip/hip_bf16.h>

// TurboQuantMSE: x_hat = Q(x @ R^T) @ R, Q = 16-level Lloyd-Max quantizer.
// fp16 MFMA GEMMs, 128x256 tile, BK=64, 8 waves, triple-buffered LDS with
// counted vmcnt(2) boundary (T3+T4), LDS XOR-swizzle (T2), setprio (T5).
// Round 4: 2 phases per K-tile with 16-MFMA clusters (m201 cluster geometry)
// instead of 4 phases x 8 MFMA — halves barrier density, doubles per-phase
// compute so cross-wave overlap hides ds_read latency.

typedef __attribute__((ext_vector_type(8))) _Float16 f16x8;
typedef __attribute__((ext_vector_type(4))) float f32x4;

__device__ __forceinline__ unsigned short f2h(float f) {
    _Float16 h = (_Float16)f;
    return *reinterpret_cast<unsigned short*>(&h);
}

// ---------------- elementwise f32 -> fp16 (x) ----------------
__global__ __launch_bounds__(256) void convert_x_kernel(
    const float* __restrict__ x, unsigned short* __restrict__ xb) {
    const int i = (blockIdx.x * 256 + threadIdx.x) * 4;
    float4 v = *reinterpret_cast<const float4*>(x + i);
    ushort4 b;
    b.x = f2h(v.x); b.y = f2h(v.y); b.z = f2h(v.z); b.w = f2h(v.w);
    *reinterpret_cast<ushort4*>(xb + i) = b;
}

// ---------------- rotation f32 -> fp16 (row-major) + fp16 transposed --------
__global__ __launch_bounds__(256) void conv_rot_kernel(
    const float* __restrict__ R, unsigned short* __restrict__ Rb,
    unsigned short* __restrict__ Rt) {
    __shared__ float t[64][65];
    const int tid = threadIdx.x;
    const int tr = blockIdx.y * 64, tc = blockIdx.x * 64;
    const int r0 = tid >> 4;
    const int c4 = (tid & 15) << 2;
#pragma unroll
    for (int i = 0; i < 4; i++) {
        const int r = r0 + i * 16;
        float4 v = *reinterpret_cast<const float4*>(
            &R[(size_t)(tr + r) * 4096 + tc + c4]);
        ushort4 b;
        b.x = f2h(v.x); b.y = f2h(v.y); b.z = f2h(v.z); b.w = f2h(v.w);
        *reinterpret_cast<ushort4*>(&Rb[(size_t)(tr + r) * 4096 + tc + c4]) = b;
        t[r][c4 + 0] = v.x; t[r][c4 + 1] = v.y;
        t[r][c4 + 2] = v.z; t[r][c4 + 3] = v.w;
    }
    __syncthreads();
#pragma unroll
    for (int i = 0; i < 16; i++) {
        const int idx = tid + 256 * i;
        const int rr = idx >> 6;
        const int cc = idx & 63;
        Rt[(size_t)(tc + rr) * 4096 + tr + cc] = f2h(t[cc][rr]);
    }
}

// ---------------- phased NT GEMM --------------------------------------------
// C[2048,4096] = A[2048,K] * Bt[4096,K]^T, fp16 in, f32 accum.
// BM=128 BN=256 BK=64, 8 waves (2M x 4N), per-wave 64x64 (4x4 frags).
// 3 LDS buffers of 48KB. 6 staging chunks/K-tile (A:2, B:4).
// Steady state: ph0 of tile t stages t+1's B (4 chunks); ph1 stages t+2's A
// (2 chunks); boundary wait = counted vmcnt(2).
constexpr int GK = 4096;
constexpr int BM = 128, BN = 256, BK = 64;
constexpr int NT = GK / BK;                 // 64
constexpr int A_BYTES = BM * BK * 2;        // 16384
constexpr int BUF_BYTES = (BM + BN) * BK * 2;  // 49152
constexpr int LDS_DYN = 3 * BUF_BYTES;      // 147456

template <bool QUANT>
__global__ __launch_bounds__(512, 2) void gemm_nt_kernel(
    const unsigned short* __restrict__ A, const unsigned short* __restrict__ Bt,
    void* __restrict__ Cout, const float* __restrict__ cb16) {
    extern __shared__ char smem[];
    const int tid = threadIdx.x;
    const int lane = tid & 63;
    const int w = tid >> 6;        // 0..7
    const int wm = w >> 2;         // 0..1
    const int wn = w & 3;          // 0..3

    // XCD-aware bijective swizzle (256 blocks, 256%8==0)
    const int bid = blockIdx.x;
    const int wgid = (bid & 7) * 32 + (bid >> 3);
    const int tn = wgid & 15;      // N/BN = 16
    const int tm = wgid >> 4;      // M/BM = 16

    f32x4 acc[4][4];
#pragma unroll
    for (int m = 0; m < 4; m++)
#pragma unroll
        for (int n = 0; n < 4; n++) acc[m][n] = (f32x4){0.f, 0.f, 0.f, 0.f};

    // ---- staging (pre-swizzled global source, linear LDS dest) ----
    const int srow = tid >> 3;                              // 0..63
    const int scol = (((tid & 7) ^ (srow & 7)) << 3);       // elements
    const size_t arow0 = (size_t)(tm * BM) * GK;
    const size_t brow0 = (size_t)(tn * BN) * GK;
    const int wbase = (w << 10);                            // w*1024 B

    auto stage = [&](int tile, int chunk) {
        const int b = tile % 3;
        const int k0 = tile * BK;
        const unsigned short* src;
        int ldsoff;
        if (chunk < 2) {
            src = A + arow0 + (size_t)(chunk * 64 + srow) * GK + k0 + scol;
            ldsoff = b * BUF_BYTES + chunk * 8192 + wbase;
        } else {
            src = Bt + brow0 + (size_t)((chunk - 2) * 64 + srow) * GK + k0 + scol;
            ldsoff = b * BUF_BYTES + A_BYTES + (chunk - 2) * 8192 + wbase;
        }
        __builtin_amdgcn_global_load_lds(
            (const __attribute__((address_space(1))) void*)src,
            (__attribute__((address_space(3))) void*)(smem + ldsoff), 16, 0, 0);
    };

    // ---- fragment read addressing (swizzled) ----
    const int arow = (wm * 64 + (lane & 15)) * 128;           // A row byte
    const int brow = A_BYTES + (wn * 64 + (lane & 15)) * 128; // B row byte
    const int slotx = lane >> 4;                              // 0..3
    const int sw0 = ((slotx ^ (lane & 7)) << 4);              // kk=0
    const int sw1 = (((4 + slotx) ^ (lane & 7)) << 4);        // kk=1

#define LDA(m, sw) (*reinterpret_cast<const f16x8*>(smem + lb + arow + (m) * 2048 + (sw)))
#define LDB(n, sw) (*reinterpret_cast<const f16x8*>(smem + lb + brow + (n) * 2048 + (sw)))
#define MFMA_ROW(aR, r)                                                          \
    acc[r][0] = __builtin_amdgcn_mfma_f32_16x16x32_f16(aR, b0, acc[r][0], 0, 0, 0); \
    acc[r][1] = __builtin_amdgcn_mfma_f32_16x16x32_f16(aR, b1, acc[r][1], 0, 0, 0); \
    acc[r][2] = __builtin_amdgcn_mfma_f32_16x16x32_f16(aR, b2, acc[r][2], 0, 0, 0); \
    acc[r][3] = __builtin_amdgcn_mfma_f32_16x16x32_f16(aR, b3, acc[r][3], 0, 0, 0);
#define PH_SYNC                                        \
    __builtin_amdgcn_s_barrier();                      \
    asm volatile("s_waitcnt lgkmcnt(0)" ::: "memory"); \
    __builtin_amdgcn_sched_barrier(0);

    // ---- prologue: tile0 fully + tile1's A chunks; wait own 6 oldest ----
    stage(0, 0); stage(0, 1); stage(0, 2); stage(0, 3); stage(0, 4); stage(0, 5);
    stage(1, 0); stage(1, 1);
    asm volatile("s_waitcnt vmcnt(2)" ::: "memory");
    __builtin_amdgcn_s_barrier();
    __builtin_amdgcn_sched_barrier(0);

    int lb = 0;
    for (int t = 0; t < NT; ++t) {
        f16x8 a0, a1, a2, a3, b0, b1, b2, b3;
        // ---- phase 0: kk=0, all 4 m-frags, 16 MFMA ----
        a0 = LDA(0, sw0); a1 = LDA(1, sw0); a2 = LDA(2, sw0); a3 = LDA(3, sw0);
        b0 = LDB(0, sw0); b1 = LDB(1, sw0); b2 = LDB(2, sw0); b3 = LDB(3, sw0);
        if (t + 1 < NT) { stage(t + 1, 2); stage(t + 1, 3);
                          stage(t + 1, 4); stage(t + 1, 5); }
        PH_SYNC
        __builtin_amdgcn_s_setprio(1);
        MFMA_ROW(a0, 0) MFMA_ROW(a1, 1) MFMA_ROW(a2, 2) MFMA_ROW(a3, 3)
        __builtin_amdgcn_s_setprio(0);
        __builtin_amdgcn_s_barrier();
        // ---- phase 1: kk=1, all 4 m-frags, 16 MFMA ----
        a0 = LDA(0, sw1); a1 = LDA(1, sw1); a2 = LDA(2, sw1); a3 = LDA(3, sw1);
        b0 = LDB(0, sw1); b1 = LDB(1, sw1); b2 = LDB(2, sw1); b3 = LDB(3, sw1);
        if (t + 2 < NT) { stage(t + 2, 0); stage(t + 2, 1); }
        PH_SYNC
        __builtin_amdgcn_s_setprio(1);
        MFMA_ROW(a0, 0) MFMA_ROW(a1, 1) MFMA_ROW(a2, 2) MFMA_ROW(a3, 3)
        __builtin_amdgcn_s_setprio(0);
        // ---- tile boundary: counted wait for next buffer's 6 chunks ----
        if (t + 1 < NT) {
            if (t + 2 < NT) {
                asm volatile("s_waitcnt vmcnt(2)" ::: "memory");
            } else {
                asm volatile("s_waitcnt vmcnt(0)" ::: "memory");
            }
            __builtin_amdgcn_s_barrier();
            __builtin_amdgcn_sched_barrier(0);
        }
        lb = (lb == 2 * BUF_BYTES) ? 0 : lb + BUF_BYTES;
    }
#undef LDA
#undef LDB
#undef MFMA_ROW
#undef PH_SYNC

    // ---- epilogue: C/D layout col=lane&15, row=(lane>>4)*4+j ----
    const int crow0 = tm * BM + wm * 64 + ((lane >> 4) << 2);
    const int ccol0 = tn * BN + wn * 64 + (lane & 15);
    if constexpr (QUANT) {
        float c[16];
#pragma unroll
        for (int i = 0; i < 16; i++) c[i] = cb16[i];
        unsigned short* O = (unsigned short*)Cout;
#pragma unroll
        for (int m = 0; m < 4; m++)
#pragma unroll
            for (int n = 0; n < 4; n++)
#pragma unroll
                for (int j = 0; j < 4; j++) {
                    const float yn = acc[m][n][j] * 64.0f;
                    float v = c[0];
#pragma unroll
                    for (int i = 0; i < 15; i++) {
                        const float bnd = 0.5f * (c[i] + c[i + 1]);
                        v = (yn > bnd) ? c[i + 1] : v;
                    }
                    O[(size_t)(crow0 + m * 16 + j) * 4096 + ccol0 + n * 16] =
                        f2h(v * 0.015625f);
                }
    } else {
        float* O = (float*)Cout;
#pragma unroll
        for (int m = 0; m < 4; m++)
#pragma unroll
            for (int n = 0; n < 4; n++)
#pragma unroll
                for (int j = 0; j < 4; j++)
                    O[(size_t)(crow0 + m * 16 + j) * 4096 + ccol0 + n * 16] =
                        acc[m][n][j];
    }
}

extern "C" void kernel_launch(void* const* d_in, const int* in_sizes, int n_in,
                              void* d_out, int out_size, void* d_ws,
                              size_t ws_size, hipStream_t stream) {
    const float* x = (const float*)d_in[0];
    const float* rot = (const float*)d_in[1];
    const float* cb = (const float*)d_in[2];
    float* out = (float*)d_out;

    unsigned short* Xh = (unsigned short*)d_ws;
    unsigned short* Rh = Xh + (size_t)2048 * 4096;
    unsigned short* Rt = Rh + (size_t)4096 * 4096;
    unsigned short* Yh = Rt + (size_t)4096 * 4096;

    (void)hipFuncSetAttribute(
        reinterpret_cast<const void*>(&gemm_nt_kernel<true>),
        hipFuncAttributeMaxDynamicSharedMemorySize, LDS_DYN);
    (void)hipFuncSetAttribute(
        reinterpret_cast<const void*>(&gemm_nt_kernel<false>),
        hipFuncAttributeMaxDynamicSharedMemorySize, LDS_DYN);

    convert_x_kernel<<<8192, 256, 0, stream>>>(x, Xh);
    conv_rot_kernel<<<dim3(64, 64), 256, 0, stream>>>(rot, Rh, Rt);
    // y = x @ R^T : NT GEMM, Bt = Rh
    gemm_nt_kernel<true><<<256, 512, LDS_DYN, stream>>>(Xh, Rh, (void*)Yh, cb);
    // x_hat = y_hat @ R = y_hat @ (R^T)^T : NT GEMM, Bt = Rt
    gemm_nt_kernel<false><<<256, 512, LDS_DYN, stream>>>(Yh, Rt, (void*)out, nullptr);
}